// Round 1
// baseline (4999.269 us; speedup 1.0000x reference)
//
#include <hip/hip_runtime.h>

// MLA shapes (fixed)
#define B_ 4
#define S_ 1024
#define H_ 4096
#define NH_ 32
#define QHD_ 192
#define EPS_ 1e-6f

typedef __bf16 bf16x8 __attribute__((ext_vector_type(8)));
typedef float floatx4 __attribute__((ext_vector_type(4)));

__device__ __forceinline__ unsigned short f2bf(float f) {
  unsigned int u = __builtin_bit_cast(unsigned int, f);
  u += 0x7fffu + ((u >> 16) & 1u);   // round-to-nearest-even (finite data only)
  return (unsigned short)(u >> 16);
}
__device__ __forceinline__ float bf2f(unsigned short s) {
  return __builtin_bit_cast(float, ((unsigned int)s) << 16);
}
__device__ __forceinline__ float bflo(unsigned int w) {
  return __builtin_bit_cast(float, w << 16);
}
__device__ __forceinline__ float bfhi(unsigned int w) {
  return __builtin_bit_cast(float, w & 0xffff0000u);
}

// ---------------------------------------------------------------------------
// Generic GEMM: C(MxN) = A(MxK) @ B(KxN). A fp32 or bf16 (converted to bf16 in
// LDS staging), B fp32, C fp32 or bf16. 128x128 tile, BK=32, 4 waves (2x2 of
// 64x64), mfma_f32_16x16x32_bf16. M%128==0, K%32==0 assumed; N guarded.
// Verified layouts (learn_hip m89/m97): a/b frag: lane holds 8 consecutive k
// at (lane>>4)*8 for row/col lane&15; C/D: row=(lane>>4)*4+r, col=lane&15.
// ---------------------------------------------------------------------------
template<bool A_F32, bool OUT_BF16>
__global__ __launch_bounds__(256, 2) void gemm_kernel(
    const void* __restrict__ Av, const float* __restrict__ Bv,
    void* __restrict__ Cv,
    const int N, const int K, const int lda, const int ldb, const int ldc)
{
  __shared__ unsigned short As[128 * 40];  // [m][k] stride 40 (pad, 16B-aligned rows)
  __shared__ unsigned short Bs[128 * 40];  // [n][k] stride 40 (B tile transposed)

  const int t = threadIdx.x;
  const int m0 = blockIdx.x * 128;
  const int n0 = blockIdx.y * 128;
  const int wid = t >> 6, lane = t & 63;
  const int wm = (wid >> 1) << 6, wn = (wid & 1) << 6;
  const int lm = lane & 15, lq = lane >> 4;

  const floatx4 vzero = {0.f, 0.f, 0.f, 0.f};
  floatx4 acc[4][4];
#pragma unroll
  for (int i = 0; i < 4; ++i)
#pragma unroll
    for (int j = 0; j < 4; ++j) acc[i][j] = vzero;

  const int ar = t >> 3, ac = (t & 7) << 2;   // A: row t/8, col 4*(t%8)
  const int br = t >> 5, bc = (t & 31) << 2;  // B: row t/32, col 4*(t%32)
  const int nk = K >> 5;

  for (int kb = 0; kb < nk; ++kb) {
    const int k0 = kb << 5;
    __syncthreads();
    // stage A tile 128x32
#pragma unroll
    for (int pp = 0; pp < 4; ++pp) {
      const int r = ar + (pp << 5);
      ushort4 w;
      if constexpr (A_F32) {
        const float4 v = *(const float4*)((const float*)Av + (size_t)(m0 + r) * lda + k0 + ac);
        w.x = f2bf(v.x); w.y = f2bf(v.y); w.z = f2bf(v.z); w.w = f2bf(v.w);
      } else {
        w = *(const ushort4*)((const unsigned short*)Av + (size_t)(m0 + r) * lda + k0 + ac);
      }
      *(ushort4*)&As[r * 40 + ac] = w;
    }
    // stage B tile 32x128, transposed into Bs[n][k]
#pragma unroll
    for (int pp = 0; pp < 4; ++pp) {
      const int r = br + (pp << 3);
      float4 v = make_float4(0.f, 0.f, 0.f, 0.f);
      if (n0 + bc < N)
        v = *(const float4*)(Bv + (size_t)(k0 + r) * ldb + n0 + bc);
      Bs[(bc + 0) * 40 + r] = f2bf(v.x);
      Bs[(bc + 1) * 40 + r] = f2bf(v.y);
      Bs[(bc + 2) * 40 + r] = f2bf(v.z);
      Bs[(bc + 3) * 40 + r] = f2bf(v.w);
    }
    __syncthreads();

    bf16x8 af[4], bfr[4];
#pragma unroll
    for (int mi = 0; mi < 4; ++mi)
      af[mi] = *(const bf16x8*)&As[(wm + mi * 16 + lm) * 40 + (lq << 3)];
#pragma unroll
    for (int ni = 0; ni < 4; ++ni)
      bfr[ni] = *(const bf16x8*)&Bs[(wn + ni * 16 + lm) * 40 + (lq << 3)];
#pragma unroll
    for (int mi = 0; mi < 4; ++mi)
#pragma unroll
      for (int ni = 0; ni < 4; ++ni)
        acc[mi][ni] = __builtin_amdgcn_mfma_f32_16x16x32_bf16(af[mi], bfr[ni], acc[mi][ni], 0, 0, 0);
  }

#pragma unroll
  for (int mi = 0; mi < 4; ++mi) {
    const int row = m0 + wm + mi * 16 + (lq << 2);
#pragma unroll
    for (int ni = 0; ni < 4; ++ni) {
      const int col = n0 + wn + ni * 16 + lm;
      if (col < N) {
#pragma unroll
        for (int r = 0; r < 4; ++r) {
          if constexpr (OUT_BF16)
            ((unsigned short*)Cv)[(size_t)(row + r) * ldc + col] = f2bf(acc[mi][ni][r]);
          else
            ((float*)Cv)[(size_t)(row + r) * ldc + col] = acc[mi][ni][r];
        }
      }
    }
  }
}

// ---------------------------------------------------------------------------
// LayerNorm in place: rows of length L (L%256==0, L<=1536), row stride given.
// ---------------------------------------------------------------------------
__global__ __launch_bounds__(256) void ln_kernel(
    float* __restrict__ x, const float* __restrict__ g,
    const float* __restrict__ bias, const int L, const int stride)
{
  __shared__ float sh[4];
  const int t = threadIdx.x;
  float* xr = x + (size_t)blockIdx.x * stride;
  const int n = L >> 8;
  float vals[6];
  float s = 0.f;
  for (int i = 0; i < n; ++i) { vals[i] = xr[t + (i << 8)]; s += vals[i]; }
#pragma unroll
  for (int off = 32; off; off >>= 1) s += __shfl_down(s, off);
  if ((t & 63) == 0) sh[t >> 6] = s;
  __syncthreads();
  const float mean = (sh[0] + sh[1] + sh[2] + sh[3]) / (float)L;
  float vs = 0.f;
  for (int i = 0; i < n; ++i) { const float d = vals[i] - mean; vs += d * d; }
#pragma unroll
  for (int off = 32; off; off >>= 1) vs += __shfl_down(vs, off);
  __syncthreads();
  if ((t & 63) == 0) sh[t >> 6] = vs;
  __syncthreads();
  const float inv = rsqrtf((sh[0] + sh[1] + sh[2] + sh[3]) / (float)L + EPS_);
  for (int i = 0; i < n; ++i) {
    const int c = t + (i << 8);
    xr[c] = (vals[i] - mean) * inv * g[c] + bias[c];
  }
}

// ---------------------------------------------------------------------------
// RoPE on q_pe (cols 128..191 of each 192-wide head), in place on bf16 q.
// One thread per (b,s,h,pair i<32): out[i]=x[i]*cos[i]-x[i+32]*sin[i];
// out[i+32]=x[i+32]*cos[i+32]+x[i]*sin[i+32].
// ---------------------------------------------------------------------------
__global__ __launch_bounds__(256) void rope_q_kernel(
    unsigned short* __restrict__ q, const float* __restrict__ cosp,
    const float* __restrict__ sinp, const int* __restrict__ pos)
{
  const int i = blockIdx.x * 256 + threadIdx.x;  // B*S*NH*32
  const int p = i & 31;
  const int h = (i >> 5) & 31;
  const int bs = i >> 10;
  const int pid = pos[bs];
  const size_t base = ((size_t)bs * NH_ + h) * QHD_ + 128;
  const float x1 = bf2f(q[base + p]);
  const float x2 = bf2f(q[base + p + 32]);
  const float* cr = cosp + (size_t)pid * 64;
  const float* sr = sinp + (size_t)pid * 64;
  q[base + p]      = f2bf(x1 * cr[p] - x2 * sr[p]);
  q[base + p + 32] = f2bf(x2 * cr[p + 32] + x1 * sr[p + 32]);
}

// RoPE on k_pe: ckv cols 512..575 (fp32) -> kpe bf16 (B,S,64)
__global__ __launch_bounds__(256) void rope_k_kernel(
    const float* __restrict__ ckv, const float* __restrict__ cosp,
    const float* __restrict__ sinp, const int* __restrict__ pos,
    unsigned short* __restrict__ kpe)
{
  const int i = blockIdx.x * 256 + threadIdx.x;  // B*S*32
  const int p = i & 31;
  const int bs = i >> 5;
  const int pid = pos[bs];
  const float* row = ckv + (size_t)bs * 576 + 512;
  const float x1 = row[p], x2 = row[p + 32];
  const float* cr = cosp + (size_t)pid * 64;
  const float* sr = sinp + (size_t)pid * 64;
  kpe[(size_t)bs * 64 + p]      = f2bf(x1 * cr[p] - x2 * sr[p]);
  kpe[(size_t)bs * 64 + p + 32] = f2bf(x2 * cr[p + 32] + x1 * sr[p + 32]);
}

// ---------------------------------------------------------------------------
// Causal attention, flash-style online softmax. Block = 256 thr = 4 waves,
// 16 q-rows per block (4 per wave), K-tiles of 64. Lanes parallel over k for
// QK (k rows from LDS, stride 194 -> conflict-free b32 reads), lanes parallel
// over d for PV. q:(B,S,NH,192) bf16; kv:(B,S,NH,256) bf16 (nope|v);
// kpe:(B,S,64) bf16; o:(B,S,NH,128) bf16.
// ---------------------------------------------------------------------------
__global__ __launch_bounds__(256) void attn_kernel(
    const unsigned short* __restrict__ q, const unsigned short* __restrict__ kv,
    const unsigned short* __restrict__ kpe, unsigned short* __restrict__ o)
{
  __shared__ float Qs[16][192];
  __shared__ unsigned short Ks[64][194];
  __shared__ unsigned short Vs[64][130];
  __shared__ float Ps[4][64];

  const int t = threadIdx.x;
  const int qt = blockIdx.x, h = blockIdx.y, b = blockIdx.z;
  const int wid = t >> 6, lane = t & 63;

  // stage Q tile (16x192) as fp32
  for (int chunk = t; chunk < 384; chunk += 256) {
    const int r = chunk / 24;
    const int c = (chunk % 24) << 3;
    const uint4 v = *(const uint4*)&q[(((size_t)b * S_ + qt * 16 + r) * NH_ + h) * QHD_ + c];
    float* dst = &Qs[r][c];
    const unsigned int wds[4] = {v.x, v.y, v.z, v.w};
#pragma unroll
    for (int i = 0; i < 4; ++i) { dst[2 * i] = bflo(wds[i]); dst[2 * i + 1] = bfhi(wds[i]); }
  }

  float mrow[4], lrow[4], acc0[4], acc1[4];
#pragma unroll
  for (int r = 0; r < 4; ++r) { mrow[r] = -INFINITY; lrow[r] = 0.f; acc0[r] = 0.f; acc1[r] = 0.f; }

  const int nkt = (qt >> 2) + 1;
  for (int kt = 0; kt < nkt; ++kt) {
    __syncthreads();
    // stage K nope (64x128 from kv)
    for (int chunk = t; chunk < 1024; chunk += 256) {
      const int r = chunk >> 4;
      const int c = (chunk & 15) << 3;
      const uint4 v = *(const uint4*)&kv[(((size_t)b * S_ + kt * 64 + r) * NH_ + h) * 256 + c];
      unsigned int* d = (unsigned int*)&Ks[r][c];
      d[0] = v.x; d[1] = v.y; d[2] = v.z; d[3] = v.w;
    }
    // stage K pe (64x64 broadcast across heads)
    for (int chunk = t; chunk < 512; chunk += 256) {
      const int r = chunk >> 3;
      const int c = (chunk & 7) << 3;
      const uint4 v = *(const uint4*)&kpe[((size_t)b * S_ + kt * 64 + r) * 64 + c];
      unsigned int* d = (unsigned int*)&Ks[r][128 + c];
      d[0] = v.x; d[1] = v.y; d[2] = v.z; d[3] = v.w;
    }
    // stage V (64x128 from kv)
    for (int chunk = t; chunk < 1024; chunk += 256) {
      const int r = chunk >> 4;
      const int c = (chunk & 15) << 3;
      const uint4 v = *(const uint4*)&kv[(((size_t)b * S_ + kt * 64 + r) * NH_ + h) * 256 + 128 + c];
      unsigned int* d = (unsigned int*)&Vs[r][c];
      d[0] = v.x; d[1] = v.y; d[2] = v.z; d[3] = v.w;
    }
    __syncthreads();

#pragma unroll
    for (int rr = 0; rr < 4; ++rr) {
      const int qi = qt * 16 + wid * 4 + rr;
      const int kidx = kt * 64 + lane;
      const unsigned int* krow = (const unsigned int*)&Ks[lane][0];
      const float* qrow = &Qs[wid * 4 + rr][0];
      float s = 0.f;
#pragma unroll 16
      for (int c = 0; c < 96; ++c) {
        const unsigned int kk = krow[c];
        s += qrow[2 * c] * bflo(kk);
        s += qrow[2 * c + 1] * bfhi(kk);
      }
      s *= 0.07216878364870322f;  // 192^-0.5
      if (kidx > qi) s = -INFINITY;
      float mx = s;
#pragma unroll
      for (int off = 32; off; off >>= 1) mx = fmaxf(mx, __shfl_xor(mx, off));
      const float nm = fmaxf(mrow[rr], mx);
      const float alpha = __expf(mrow[rr] - nm);
      const float p = __expf(s - nm);
      mrow[rr] = nm;
      float ps = p;
#pragma unroll
      for (int off = 32; off; off >>= 1) ps += __shfl_xor(ps, off);
      lrow[rr] = lrow[rr] * alpha + ps;
      acc0[rr] *= alpha;
      acc1[rr] *= alpha;
      __syncthreads();           // WAR on Ps across rr iterations (uniform trip count)
      Ps[wid][lane] = p;
      __syncthreads();           // make Ps visible before PV
#pragma unroll 8
      for (int j = 0; j < 64; ++j) {
        const float pv = Ps[wid][j];
        acc0[rr] += pv * bf2f(Vs[j][lane]);
        acc1[rr] += pv * bf2f(Vs[j][lane + 64]);
      }
    }
  }

#pragma unroll
  for (int rr = 0; rr < 4; ++rr) {
    const int qi = qt * 16 + wid * 4 + rr;
    const float inv = 1.f / lrow[rr];
    const size_t ob = (((size_t)b * S_ + qi) * NH_ + h) * 128;
    o[ob + lane] = f2bf(acc0[rr] * inv);
    o[ob + lane + 64] = f2bf(acc1[rr] * inv);
  }
}

// ---------------------------------------------------------------------------
extern "C" void kernel_launch(void* const* d_in, const int* in_sizes, int n_in,
                              void* d_out, int out_size, void* d_ws, size_t ws_size,
                              hipStream_t stream) {
  (void)in_sizes; (void)n_in; (void)out_size; (void)ws_size;
  const float* hs   = (const float*)d_in[0];
  const float* cosp = (const float*)d_in[1];
  const float* sinp = (const float*)d_in[2];
  const int*   pos  = (const int*)d_in[3];
  const float* Wqa  = (const float*)d_in[4];
  const float* gqa  = (const float*)d_in[5];
  const float* bqa  = (const float*)d_in[6];
  const float* Wqb  = (const float*)d_in[7];
  const float* Wkva = (const float*)d_in[8];
  const float* gkva = (const float*)d_in[9];
  const float* bkva = (const float*)d_in[10];
  const float* Wkvb = (const float*)d_in[11];
  const float* Wo   = (const float*)d_in[12];
  float* out = (float*)d_out;

  char* ws = (char*)d_ws;
  // workspace layout (total ~177.5 MiB)
  float* q_a          = (float*)(ws);                      // 4096x1536 f32 = 25165824 B
  float* ckv          = (float*)(ws + 25165824);           // 4096x576  f32 =  9437184 B
  unsigned short* qb  = (unsigned short*)(ws + 34603008);  // 4096x6144 bf16 = 50331648 B
  unsigned short* kvb = (unsigned short*)(ws + 84934656);  // 4096x8192 bf16 = 67108864 B
  unsigned short* kpe = (unsigned short*)(ws + 152043520); // 4096x64   bf16 =   524288 B
  unsigned short* ob  = (unsigned short*)(ws + 152567808); // 4096x4096 bf16 = 33554432 B

  const dim3 blk(256);
  // q_a = hs @ Wqa  (fp32 out, LN next)
  gemm_kernel<true, false><<<dim3(32, 12), blk, 0, stream>>>(hs, Wqa, q_a, 1536, 4096, 4096, 1536, 1536);
  // ckv = hs @ Wkva (fp32 out, LN + rope next); N=576 ragged
  gemm_kernel<true, false><<<dim3(32, 5), blk, 0, stream>>>(hs, Wkva, ckv, 576, 4096, 4096, 576, 576);
  ln_kernel<<<dim3(4096), blk, 0, stream>>>(q_a, gqa, bqa, 1536, 1536);
  ln_kernel<<<dim3(4096), blk, 0, stream>>>(ckv, gkva, bkva, 512, 576);
  rope_k_kernel<<<dim3(512), blk, 0, stream>>>(ckv, cosp, sinp, pos, kpe);
  // q = ln(q_a) @ Wqb (bf16 out)
  gemm_kernel<true, true><<<dim3(32, 48), blk, 0, stream>>>(q_a, Wqb, qb, 6144, 1536, 1536, 6144, 6144);
  rope_q_kernel<<<dim3(16384), blk, 0, stream>>>(qb, cosp, sinp, pos);
  // kv = ln(kv_c) @ Wkvb (bf16 out); A is first 512 cols of ckv, lda=576
  gemm_kernel<true, true><<<dim3(32, 64), blk, 0, stream>>>(ckv, Wkvb, kvb, 8192, 512, 576, 8192, 8192);
  attn_kernel<<<dim3(64, 32, 4), blk, 0, stream>>>(qb, kvb, kpe, ob);
  // out = o @ Wo (A bf16, fp32 out)
  gemm_kernel<false, false><<<dim3(32, 32), blk, 0, stream>>>(ob, Wo, out, 4096, 4096, 4096, 4096, 4096);
}

// Round 2
// 2399.373 us; speedup vs baseline: 2.0836x; 2.0836x over previous
//
#include <hip/hip_runtime.h>

// MLA shapes (fixed)
#define B_ 4
#define S_ 1024
#define H_ 4096
#define NH_ 32
#define QHD_ 192
#define EPS_ 1e-6f

typedef __bf16 bf16x8 __attribute__((ext_vector_type(8)));
typedef float floatx4 __attribute__((ext_vector_type(4)));

__device__ __forceinline__ unsigned short f2bf(float f) {
  unsigned int u = __builtin_bit_cast(unsigned int, f);
  u += 0x7fffu + ((u >> 16) & 1u);   // round-to-nearest-even (finite data only)
  return (unsigned short)(u >> 16);
}
__device__ __forceinline__ float bf2f(unsigned short s) {
  return __builtin_bit_cast(float, ((unsigned int)s) << 16);
}

// ---------------------------------------------------------------------------
// Generic GEMM: C(MxN) = A(MxK) @ B(KxN). A fp32 or bf16 (converted to bf16 in
// LDS staging), B fp32. OMODE: 0 = fp32 row-major, 1 = bf16 row-major,
// 2 = bf16 scattered to (B, NH, S, 256) "kv" layout (head-contiguous for attn).
// 128x128 tile, BK=32, 4 waves (2x2 of 64x64), mfma_f32_16x16x32_bf16.
// ---------------------------------------------------------------------------
template<bool A_F32, int OMODE>
__global__ __launch_bounds__(256, 2) void gemm_kernel(
    const void* __restrict__ Av, const float* __restrict__ Bv,
    void* __restrict__ Cv,
    const int N, const int K, const int lda, const int ldb, const int ldc)
{
  __shared__ unsigned short As[128 * 40];  // [m][k] stride 40
  __shared__ unsigned short Bs[128 * 40];  // [n][k] stride 40 (B tile transposed)

  const int t = threadIdx.x;
  const int m0 = blockIdx.x * 128;
  const int n0 = blockIdx.y * 128;
  const int wid = t >> 6, lane = t & 63;
  const int wm = (wid >> 1) << 6, wn = (wid & 1) << 6;
  const int lm = lane & 15, lq = lane >> 4;

  const floatx4 vzero = {0.f, 0.f, 0.f, 0.f};
  floatx4 acc[4][4];
#pragma unroll
  for (int i = 0; i < 4; ++i)
#pragma unroll
    for (int j = 0; j < 4; ++j) acc[i][j] = vzero;

  const int ar = t >> 3, ac = (t & 7) << 2;   // A: row t/8, col 4*(t%8)
  const int br = t >> 5, bc = (t & 31) << 2;  // B: row t/32, col 4*(t%32)
  const int nk = K >> 5;

  for (int kb = 0; kb < nk; ++kb) {
    const int k0 = kb << 5;
    __syncthreads();
#pragma unroll
    for (int pp = 0; pp < 4; ++pp) {
      const int r = ar + (pp << 5);
      ushort4 w;
      if constexpr (A_F32) {
        const float4 v = *(const float4*)((const float*)Av + (size_t)(m0 + r) * lda + k0 + ac);
        w.x = f2bf(v.x); w.y = f2bf(v.y); w.z = f2bf(v.z); w.w = f2bf(v.w);
      } else {
        w = *(const ushort4*)((const unsigned short*)Av + (size_t)(m0 + r) * lda + k0 + ac);
      }
      *(ushort4*)&As[r * 40 + ac] = w;
    }
#pragma unroll
    for (int pp = 0; pp < 4; ++pp) {
      const int r = br + (pp << 3);
      float4 v = make_float4(0.f, 0.f, 0.f, 0.f);
      if (n0 + bc < N)
        v = *(const float4*)(Bv + (size_t)(k0 + r) * ldb + n0 + bc);
      Bs[(bc + 0) * 40 + r] = f2bf(v.x);
      Bs[(bc + 1) * 40 + r] = f2bf(v.y);
      Bs[(bc + 2) * 40 + r] = f2bf(v.z);
      Bs[(bc + 3) * 40 + r] = f2bf(v.w);
    }
    __syncthreads();

    bf16x8 af[4], bfr[4];
#pragma unroll
    for (int mi = 0; mi < 4; ++mi)
      af[mi] = *(const bf16x8*)&As[(wm + mi * 16 + lm) * 40 + (lq << 3)];
#pragma unroll
    for (int ni = 0; ni < 4; ++ni)
      bfr[ni] = *(const bf16x8*)&Bs[(wn + ni * 16 + lm) * 40 + (lq << 3)];
#pragma unroll
    for (int mi = 0; mi < 4; ++mi)
#pragma unroll
      for (int ni = 0; ni < 4; ++ni)
        acc[mi][ni] = __builtin_amdgcn_mfma_f32_16x16x32_bf16(af[mi], bfr[ni], acc[mi][ni], 0, 0, 0);
  }

#pragma unroll
  for (int mi = 0; mi < 4; ++mi) {
    const int row = m0 + wm + mi * 16 + (lq << 2);
#pragma unroll
    for (int ni = 0; ni < 4; ++ni) {
      const int col = n0 + wn + ni * 16 + lm;
      if (col < N) {
#pragma unroll
        for (int r = 0; r < 4; ++r) {
          if constexpr (OMODE == 0)
            ((float*)Cv)[(size_t)(row + r) * ldc + col] = acc[mi][ni][r];
          else if constexpr (OMODE == 1)
            ((unsigned short*)Cv)[(size_t)(row + r) * ldc + col] = f2bf(acc[mi][ni][r]);
          else {
            const int rr2 = row + r;  // (B,NH,S,256) layout: h=col>>8, d=col&255
            ((unsigned short*)Cv)[(((size_t)(rr2 >> 10) * NH_ + (col >> 8)) * S_ + (rr2 & 1023)) * 256 + (col & 255)] = f2bf(acc[mi][ni][r]);
          }
        }
      }
    }
  }
}

// ---------------------------------------------------------------------------
// LayerNorm in place: rows of length L (L%256==0), row stride given.
// ---------------------------------------------------------------------------
__global__ __launch_bounds__(256) void ln_kernel(
    float* __restrict__ x, const float* __restrict__ g,
    const float* __restrict__ bias, const int L, const int stride)
{
  __shared__ float sh[4];
  const int t = threadIdx.x;
  float* xr = x + (size_t)blockIdx.x * stride;
  const int n = L >> 8;
  float vals[6];
  float s = 0.f;
  for (int i = 0; i < n; ++i) { vals[i] = xr[t + (i << 8)]; s += vals[i]; }
#pragma unroll
  for (int off = 32; off; off >>= 1) s += __shfl_down(s, off);
  if ((t & 63) == 0) sh[t >> 6] = s;
  __syncthreads();
  const float mean = (sh[0] + sh[1] + sh[2] + sh[3]) / (float)L;
  float vs = 0.f;
  for (int i = 0; i < n; ++i) { const float d = vals[i] - mean; vs += d * d; }
#pragma unroll
  for (int off = 32; off; off >>= 1) vs += __shfl_down(vs, off);
  __syncthreads();
  if ((t & 63) == 0) sh[t >> 6] = vs;
  __syncthreads();
  const float inv = rsqrtf((sh[0] + sh[1] + sh[2] + sh[3]) / (float)L + EPS_);
  for (int i = 0; i < n; ++i) {
    const int c = t + (i << 8);
    xr[c] = (vals[i] - mean) * inv * g[c] + bias[c];
  }
}

// ---------------------------------------------------------------------------
// RoPE on q_pe (cols 128..191 of each 192-wide head), in place on bf16 q.
// ---------------------------------------------------------------------------
__global__ __launch_bounds__(256) void rope_q_kernel(
    unsigned short* __restrict__ q, const float* __restrict__ cosp,
    const float* __restrict__ sinp, const int* __restrict__ pos)
{
  const int i = blockIdx.x * 256 + threadIdx.x;  // B*S*NH*32
  const int p = i & 31;
  const int h = (i >> 5) & 31;
  const int bs = i >> 10;
  const int pid = pos[bs];
  const size_t base = ((size_t)bs * NH_ + h) * QHD_ + 128;
  const float x1 = bf2f(q[base + p]);
  const float x2 = bf2f(q[base + p + 32]);
  const float* cr = cosp + (size_t)pid * 64;
  const float* sr = sinp + (size_t)pid * 64;
  q[base + p]      = f2bf(x1 * cr[p] - x2 * sr[p]);
  q[base + p + 32] = f2bf(x2 * cr[p + 32] + x1 * sr[p + 32]);
}

// RoPE on k_pe: ckv cols 512..575 (fp32) -> kpe bf16 (B,S,64)
__global__ __launch_bounds__(256) void rope_k_kernel(
    const float* __restrict__ ckv, const float* __restrict__ cosp,
    const float* __restrict__ sinp, const int* __restrict__ pos,
    unsigned short* __restrict__ kpe)
{
  const int i = blockIdx.x * 256 + threadIdx.x;  // B*S*32
  const int p = i & 31;
  const int bs = i >> 5;
  const int pid = pos[bs];
  const float* row = ckv + (size_t)bs * 576 + 512;
  const float x1 = row[p], x2 = row[p + 32];
  const float* cr = cosp + (size_t)pid * 64;
  const float* sr = sinp + (size_t)pid * 64;
  kpe[(size_t)bs * 64 + p]      = f2bf(x1 * cr[p] - x2 * sr[p]);
  kpe[(size_t)bs * 64 + p + 32] = f2bf(x2 * cr[p + 32] + x1 * sr[p + 32]);
}

// ---------------------------------------------------------------------------
// MFMA flash attention. Block = 4 waves; block handles (b, h, 64 q-rows).
// Wave w owns q-rows [w*16, w*16+16). Q (16x192) held in registers as 6
// A-frags. Per 64-k-tile: K (64x192 = nope|pe) staged in LDS row-major,
// V staged TRANSPOSED (Vt[128 vd][64 k]) for clean B-frag b128 reads.
// QK^T -> online softmax in C-layout (row=(lane>>4)*4+r, col=lane&15) ->
// P through per-wave LDS into A-layout -> PV. kvb layout (B,NH,S,256).
// qt reversed (longest blocks first) for tail.
// ---------------------------------------------------------------------------
__global__ __launch_bounds__(256) void attn_kernel(
    const unsigned short* __restrict__ qb, const unsigned short* __restrict__ kvb,
    const unsigned short* __restrict__ kpe, unsigned short* __restrict__ o)
{
  __shared__ unsigned short Ks[64 * 200];      // [k][d 0..191], stride 200
  __shared__ unsigned short Vt[128 * 72];      // [vd][k], stride 72
  __shared__ unsigned short Ps[4 * 16 * 72];   // per-wave [m][k], stride 72

  const int t = threadIdx.x;
  const int qt = (int)gridDim.x - 1 - (int)blockIdx.x;  // longest first
  const int h = blockIdx.y, b = blockIdx.z;
  const int w = t >> 6, lane = t & 63;
  const int lm = lane & 15, lq = lane >> 4;
  const float SCALE = 0.07216878364870322f;  // 192^-0.5

  // Q fragments (row = lm within wave's 16, k = s*32 + lq*8)
  const unsigned short* qp = qb + (((size_t)b * S_ + (qt << 6) + (w << 4) + lm) * NH_ + h) * QHD_;
  bf16x8 qf[6];
#pragma unroll
  for (int s = 0; s < 6; ++s) qf[s] = *(const bf16x8*)(qp + s * 32 + (lq << 3));

  const floatx4 vzero = {0.f, 0.f, 0.f, 0.f};
  floatx4 of[8];
#pragma unroll
  for (int i = 0; i < 8; ++i) of[i] = vzero;
  float mrow[4] = {-1e30f, -1e30f, -1e30f, -1e30f};
  float lrow[4] = {0.f, 0.f, 0.f, 0.f};

  const unsigned short* kvbase = kvb + (size_t)(b * NH_ + h) * S_ * 256;
  const unsigned short* kpbase = kpe + (size_t)b * S_ * 64;

  for (int kt = 0; kt <= qt; ++kt) {
    const unsigned short* kvt = kvbase + (size_t)(kt << 6) * 256;
    const unsigned short* kpt = kpbase + (size_t)(kt << 6) * 64;
    __syncthreads();
    // K nope: 64 rows x 128, coalesced 16B
#pragma unroll
    for (int it = 0; it < 4; ++it) {
      const int c = it * 256 + t;
      const int r = c >> 4, cc = (c & 15) << 3;
      *(uint4*)&Ks[r * 200 + cc] = *(const uint4*)(kvt + r * 256 + cc);
    }
    // K pe: 64 rows x 64
#pragma unroll
    for (int it = 0; it < 2; ++it) {
      const int c = it * 256 + t;
      const int r = c >> 3, cc = (c & 7) << 3;
      *(uint4*)&Ks[r * 200 + 128 + cc] = *(const uint4*)(kpt + r * 64 + cc);
    }
    // V transposed: thread reads 2 k-rows x 8 vd, writes 8 u32 (2 k per vd)
#pragma unroll
    for (int it = 0; it < 2; ++it) {
      const int idx = it * 256 + t;
      const int cg = idx & 15, kp = idx >> 4;
      const unsigned short* p0 = kvt + (kp << 1) * 256 + 128 + (cg << 3);
      const uint4 va = *(const uint4*)p0;
      const uint4 vb = *(const uint4*)(p0 + 256);
      const unsigned short* ap = (const unsigned short*)&va;
      const unsigned short* bp = (const unsigned short*)&vb;
#pragma unroll
      for (int i = 0; i < 8; ++i)
        *(unsigned int*)&Vt[((cg << 3) + i) * 72 + (kp << 1)] =
            (unsigned int)ap[i] | ((unsigned int)bp[i] << 16);
    }
    __syncthreads();

    const bool diag = (kt == qt);
    const int nimax = diag ? w : 3;

    // S = Q K^T (wave tile 16x64)
    floatx4 sacc[4];
#pragma unroll
    for (int ni = 0; ni < 4; ++ni) sacc[ni] = vzero;
    for (int ni = 0; ni <= nimax; ++ni) {
#pragma unroll
      for (int s = 0; s < 6; ++s) {
        const bf16x8 kf = *(const bf16x8*)&Ks[(ni * 16 + lm) * 200 + s * 32 + (lq << 3)];
        sacc[ni] = __builtin_amdgcn_mfma_f32_16x16x32_bf16(qf[s], kf, sacc[ni], 0, 0, 0);
      }
    }

    // online softmax per row (rq = lq*4 + r), cols = ni*16 + lm
#pragma unroll
    for (int r = 0; r < 4; ++r) {
      const int rq = (lq << 2) + r;
      float sc[4], mx = -1e30f;
#pragma unroll
      for (int ni = 0; ni < 4; ++ni) {
        float v = sacc[ni][r] * SCALE;
        if (ni > nimax) v = -1e30f;
        if (diag && ni == w && lm > rq) v = -1e30f;
        sc[ni] = v;
        mx = fmaxf(mx, v);
      }
#pragma unroll
      for (int off = 8; off; off >>= 1) mx = fmaxf(mx, __shfl_xor(mx, off));
      const float mnew = fmaxf(mrow[r], mx);
      const float al = __expf(mrow[r] - mnew);
      mrow[r] = mnew;
      float ps = 0.f;
#pragma unroll
      for (int ni = 0; ni < 4; ++ni) {
        const float p = __expf(sc[ni] - mnew);
        ps += p;
        Ps[(w * 16 + rq) * 72 + ni * 16 + lm] = f2bf(p);
      }
#pragma unroll
      for (int off = 8; off; off >>= 1) ps += __shfl_xor(ps, off);
      lrow[r] = lrow[r] * al + ps;
#pragma unroll
      for (int vt = 0; vt < 8; ++vt) of[vt][r] *= al;
    }

    // O += P V  (P A-frags from per-wave LDS; no barrier needed: wave-private)
    const int ksmax = diag ? ((w >= 2) ? 1 : 0) : 1;
    for (int ks2 = 0; ks2 <= ksmax; ++ks2) {
      const bf16x8 pf = *(const bf16x8*)&Ps[(w * 16 + lm) * 72 + ks2 * 32 + (lq << 3)];
#pragma unroll
      for (int vt = 0; vt < 8; ++vt) {
        const bf16x8 vf = *(const bf16x8*)&Vt[(vt * 16 + lm) * 72 + ks2 * 32 + (lq << 3)];
        of[vt] = __builtin_amdgcn_mfma_f32_16x16x32_bf16(pf, vf, of[vt], 0, 0, 0);
      }
    }
  }

  // epilogue: divide by l, store o (B,S,NH*128)
#pragma unroll
  for (int r = 0; r < 4; ++r) {
    const int qrow = (qt << 6) + (w << 4) + (lq << 2) + r;
    const float inv = 1.f / lrow[r];
    unsigned short* orow = o + ((size_t)b * S_ + qrow) * 4096 + h * 128;
#pragma unroll
    for (int vt = 0; vt < 8; ++vt)
      orow[vt * 16 + lm] = f2bf(of[vt][r] * inv);
  }
}

// ---------------------------------------------------------------------------
extern "C" void kernel_launch(void* const* d_in, const int* in_sizes, int n_in,
                              void* d_out, int out_size, void* d_ws, size_t ws_size,
                              hipStream_t stream) {
  (void)in_sizes; (void)n_in; (void)out_size; (void)ws_size;
  const float* hs   = (const float*)d_in[0];
  const float* cosp = (const float*)d_in[1];
  const float* sinp = (const float*)d_in[2];
  const int*   pos  = (const int*)d_in[3];
  const float* Wqa  = (const float*)d_in[4];
  const float* gqa  = (const float*)d_in[5];
  const float* bqa  = (const float*)d_in[6];
  const float* Wqb  = (const float*)d_in[7];
  const float* Wkva = (const float*)d_in[8];
  const float* gkva = (const float*)d_in[9];
  const float* bkva = (const float*)d_in[10];
  const float* Wkvb = (const float*)d_in[11];
  const float* Wo   = (const float*)d_in[12];
  float* out = (float*)d_out;

  char* ws = (char*)d_ws;
  float* q_a          = (float*)(ws);                      // 4096x1536 f32
  float* ckv          = (float*)(ws + 25165824);           // 4096x576  f32
  unsigned short* qb  = (unsigned short*)(ws + 34603008);  // 4096x6144 bf16 (B,S,NH,192)
  unsigned short* kvb = (unsigned short*)(ws + 84934656);  // bf16 (B,NH,S,256)
  unsigned short* kpe = (unsigned short*)(ws + 152043520); // 4096x64   bf16
  unsigned short* ob  = (unsigned short*)(ws + 152567808); // 4096x4096 bf16

  const dim3 blk(256);
  gemm_kernel<true, 0><<<dim3(32, 12), blk, 0, stream>>>(hs, Wqa, q_a, 1536, 4096, 4096, 1536, 1536);
  gemm_kernel<true, 0><<<dim3(32, 5), blk, 0, stream>>>(hs, Wkva, ckv, 576, 4096, 4096, 576, 576);
  ln_kernel<<<dim3(4096), blk, 0, stream>>>(q_a, gqa, bqa, 1536, 1536);
  ln_kernel<<<dim3(4096), blk, 0, stream>>>(ckv, gkva, bkva, 512, 576);
  rope_k_kernel<<<dim3(512), blk, 0, stream>>>(ckv, cosp, sinp, pos, kpe);
  gemm_kernel<true, 1><<<dim3(32, 48), blk, 0, stream>>>(q_a, Wqb, qb, 6144, 1536, 1536, 6144, 6144);
  rope_q_kernel<<<dim3(16384), blk, 0, stream>>>(qb, cosp, sinp, pos);
  gemm_kernel<true, 2><<<dim3(32, 64), blk, 0, stream>>>(ckv, Wkvb, kvb, 8192, 512, 576, 8192, 8192);
  attn_kernel<<<dim3(16, 32, 4), blk, 0, stream>>>(qb, kvb, kpe, ob);
  gemm_kernel<false, 0><<<dim3(32, 32), blk, 0, stream>>>(ob, Wo, out, 4096, 4096, 4096, 4096, 4096);
}

// Round 3
// 1143.455 us; speedup vs baseline: 4.3721x; 2.0984x over previous
//
#include <hip/hip_runtime.h>

// MLA shapes (fixed)
#define B_ 4
#define S_ 1024
#define H_ 4096
#define NH_ 32
#define QHD_ 192
#define EPS_ 1e-6f

typedef __bf16 bf16x8 __attribute__((ext_vector_type(8)));
typedef float floatx4 __attribute__((ext_vector_type(4)));

__device__ __forceinline__ unsigned short f2bf(float f) {
  unsigned int u = __builtin_bit_cast(unsigned int, f);
  u += 0x7fffu + ((u >> 16) & 1u);   // round-to-nearest-even (finite data only)
  return (unsigned short)(u >> 16);
}
__device__ __forceinline__ float bf2f(unsigned short s) {
  return __builtin_bit_cast(float, ((unsigned int)s) << 16);
}

// async global->LDS, 16B per lane; LDS dest = wave-uniform base + lane*16 (m104)
__device__ __forceinline__ void gload16(const unsigned short* g, unsigned short* l) {
  __builtin_amdgcn_global_load_lds(
      (const __attribute__((address_space(1))) void*)g,
      (__attribute__((address_space(3))) void*)l, 16, 0, 0);
}

// ---------------------------------------------------------------------------
// fp32 -> bf16 convert (hs), 8 elems/thread
// ---------------------------------------------------------------------------
__global__ __launch_bounds__(256) void convert_kernel(
    const float* __restrict__ x, unsigned short* __restrict__ y)
{
  const int i = (blockIdx.x * 256 + threadIdx.x) * 8;
  const float4 a = *(const float4*)(x + i);
  const float4 b = *(const float4*)(x + i + 4);
  ushort4 u, v;
  u.x = f2bf(a.x); u.y = f2bf(a.y); u.z = f2bf(a.z); u.w = f2bf(a.w);
  v.x = f2bf(b.x); v.y = f2bf(b.y); v.z = f2bf(b.z); v.w = f2bf(b.w);
  *(ushort4*)(y + i) = u;
  *(ushort4*)(y + i + 4) = v;
}

// ---------------------------------------------------------------------------
// W (KxN fp32 row-major) -> Wt (NxK bf16 row-major). 32x32 LDS tiles.
// ---------------------------------------------------------------------------
__global__ __launch_bounds__(256) void transpose_kernel(
    const float* __restrict__ W, unsigned short* __restrict__ Wt,
    const int K, const int N)
{
  __shared__ float tile[32][33];
  const int tx = threadIdx.x & 31, ty = threadIdx.x >> 5;
  const int nb = blockIdx.x << 5, kb = blockIdx.y << 5;
#pragma unroll
  for (int j = 0; j < 4; ++j)
    tile[ty + j * 8][tx] = W[(size_t)(kb + ty + j * 8) * N + nb + tx];
  __syncthreads();
#pragma unroll
  for (int j = 0; j < 4; ++j)
    Wt[(size_t)(nb + ty + j * 8) * K + kb + tx] = f2bf(tile[tx][ty + j * 8]);
}

// ---------------------------------------------------------------------------
// m97-class GEMM: C(MxN) = A(MxK) @ Bt(NxK)^T, both bf16, staged via
// global_load_lds width=16 into unpadded LDS [128][32]. 128x128 tile, BK=32,
// 4 waves (2x2 of 64x64), mfma_f32_16x16x32_bf16.
// OMODE: 0 = fp32 row-major, 1 = bf16 row-major, 2 = bf16 (B,NH,S,256) kv.
// M%128==0, K%32==0; Bt rows padded to 128-mult (pad contents finite poison).
// ---------------------------------------------------------------------------
template<int OMODE>
__global__ __launch_bounds__(256, 2) void gemm_bt(
    const unsigned short* __restrict__ A, const unsigned short* __restrict__ Bt,
    void* __restrict__ Cv, const int N, const int K,
    const int lda, const int ldb, const int ldc)
{
  __shared__ unsigned short As[128 * 32];
  __shared__ unsigned short Bs[128 * 32];

  const int t = threadIdx.x;
  const int m0 = blockIdx.x * 128, n0 = blockIdx.y * 128;
  const int w = t >> 6, lane = t & 63;
  const int wm = (w >> 1) << 6, wn = (w & 1) << 6;
  const int lm = lane & 15, lq = lane >> 4;

  const floatx4 vzero = {0.f, 0.f, 0.f, 0.f};
  floatx4 acc[4][4];
#pragma unroll
  for (int i = 0; i < 4; ++i)
#pragma unroll
    for (int j = 0; j < 4; ++j) acc[i][j] = vzero;

  // staging: wave w does calls i=0,1; call covers 16 rows x 32 cols (1 KB).
  // lane -> row (w*32 + i*16 + lane/4), chunk kc = lane&3 (8 shorts).
  const int srow = (w << 5) + (lane >> 2);
  const int skc = (lane & 3) << 3;
  const unsigned short* gA = A + (size_t)(m0 + srow) * lda + skc;
  const unsigned short* gB = Bt + (size_t)(n0 + srow) * ldb + skc;
  unsigned short* lA0 = &As[(w << 1) * 512];
  unsigned short* lA1 = &As[((w << 1) + 1) * 512];
  unsigned short* lB0 = &Bs[(w << 1) * 512];
  unsigned short* lB1 = &Bs[((w << 1) + 1) * 512];

  const int nk = K >> 5;
  for (int kb = 0; kb < nk; ++kb) {
    const int k0 = kb << 5;
    __syncthreads();
    gload16(gA + k0, lA0);
    gload16(gA + (size_t)16 * lda + k0, lA1);
    gload16(gB + k0, lB0);
    gload16(gB + (size_t)16 * ldb + k0, lB1);
    __syncthreads();

    bf16x8 af[4], bfr[4];
#pragma unroll
    for (int mi = 0; mi < 4; ++mi)
      af[mi] = *(const bf16x8*)&As[(wm + mi * 16 + lm) * 32 + (lq << 3)];
#pragma unroll
    for (int ni = 0; ni < 4; ++ni)
      bfr[ni] = *(const bf16x8*)&Bs[(wn + ni * 16 + lm) * 32 + (lq << 3)];
#pragma unroll
    for (int mi = 0; mi < 4; ++mi)
#pragma unroll
      for (int ni = 0; ni < 4; ++ni)
        acc[mi][ni] = __builtin_amdgcn_mfma_f32_16x16x32_bf16(af[mi], bfr[ni], acc[mi][ni], 0, 0, 0);
  }

#pragma unroll
  for (int mi = 0; mi < 4; ++mi) {
    const int row = m0 + wm + mi * 16 + (lq << 2);
#pragma unroll
    for (int ni = 0; ni < 4; ++ni) {
      const int col = n0 + wn + ni * 16 + lm;
      if (col < N) {
#pragma unroll
        for (int r = 0; r < 4; ++r) {
          if constexpr (OMODE == 0)
            ((float*)Cv)[(size_t)(row + r) * ldc + col] = acc[mi][ni][r];
          else if constexpr (OMODE == 1)
            ((unsigned short*)Cv)[(size_t)(row + r) * ldc + col] = f2bf(acc[mi][ni][r]);
          else {
            const int rr2 = row + r;  // (B,NH,S,256): h=col>>8, d=col&255
            ((unsigned short*)Cv)[(((size_t)(rr2 >> 10) * NH_ + (col >> 8)) * S_ + (rr2 & 1023)) * 256 + (col & 255)] = f2bf(acc[mi][ni][r]);
          }
        }
      }
    }
  }
}

// ---------------------------------------------------------------------------
// LayerNorm: x fp32 rows (len L, stride xstride) -> y bf16 (stride ystride).
// ---------------------------------------------------------------------------
__global__ __launch_bounds__(256) void ln_kernel(
    const float* __restrict__ x, const float* __restrict__ g,
    const float* __restrict__ bias, unsigned short* __restrict__ y,
    const int L, const int xstride, const int ystride)
{
  __shared__ float sh[4];
  const int t = threadIdx.x;
  const float* xr = x + (size_t)blockIdx.x * xstride;
  unsigned short* yr = y + (size_t)blockIdx.x * ystride;
  const int n = L >> 8;
  float vals[6];
  float s = 0.f;
  for (int i = 0; i < n; ++i) { vals[i] = xr[t + (i << 8)]; s += vals[i]; }
#pragma unroll
  for (int off = 32; off; off >>= 1) s += __shfl_down(s, off);
  if ((t & 63) == 0) sh[t >> 6] = s;
  __syncthreads();
  const float mean = (sh[0] + sh[1] + sh[2] + sh[3]) / (float)L;
  float vs = 0.f;
  for (int i = 0; i < n; ++i) { const float d = vals[i] - mean; vs += d * d; }
#pragma unroll
  for (int off = 32; off; off >>= 1) vs += __shfl_down(vs, off);
  __syncthreads();
  if ((t & 63) == 0) sh[t >> 6] = vs;
  __syncthreads();
  const float inv = rsqrtf((sh[0] + sh[1] + sh[2] + sh[3]) / (float)L + EPS_);
  for (int i = 0; i < n; ++i) {
    const int c = t + (i << 8);
    yr[c] = f2bf((vals[i] - mean) * inv * g[c] + bias[c]);
  }
}

// ---------------------------------------------------------------------------
// RoPE on q_pe (cols 128..191 of each 192-wide head), in place on bf16 q.
// ---------------------------------------------------------------------------
__global__ __launch_bounds__(256) void rope_q_kernel(
    unsigned short* __restrict__ q, const float* __restrict__ cosp,
    const float* __restrict__ sinp, const int* __restrict__ pos)
{
  const int i = blockIdx.x * 256 + threadIdx.x;  // B*S*NH*32
  const int p = i & 31;
  const int h = (i >> 5) & 31;
  const int bs = i >> 10;
  const int pid = pos[bs];
  const size_t base = ((size_t)bs * NH_ + h) * QHD_ + 128;
  const float x1 = bf2f(q[base + p]);
  const float x2 = bf2f(q[base + p + 32]);
  const float* cr = cosp + (size_t)pid * 64;
  const float* sr = sinp + (size_t)pid * 64;
  q[base + p]      = f2bf(x1 * cr[p] - x2 * sr[p]);
  q[base + p + 32] = f2bf(x2 * cr[p + 32] + x1 * sr[p + 32]);
}

// RoPE on k_pe: ckv cols 512..575 (fp32) -> kpe bf16 (B,S,64)
__global__ __launch_bounds__(256) void rope_k_kernel(
    const float* __restrict__ ckv, const float* __restrict__ cosp,
    const float* __restrict__ sinp, const int* __restrict__ pos,
    unsigned short* __restrict__ kpe)
{
  const int i = blockIdx.x * 256 + threadIdx.x;  // B*S*32
  const int p = i & 31;
  const int bs = i >> 5;
  const int pid = pos[bs];
  const float* row = ckv + (size_t)bs * 576 + 512;
  const float x1 = row[p], x2 = row[p + 32];
  const float* cr = cosp + (size_t)pid * 64;
  const float* sr = sinp + (size_t)pid * 64;
  kpe[(size_t)bs * 64 + p]      = f2bf(x1 * cr[p] - x2 * sr[p]);
  kpe[(size_t)bs * 64 + p + 32] = f2bf(x2 * cr[p + 32] + x1 * sr[p + 32]);
}

// ---------------------------------------------------------------------------
// MFMA flash attention (unchanged from round 2). Block = 4 waves = (b,h,64 q).
// ---------------------------------------------------------------------------
__global__ __launch_bounds__(256) void attn_kernel(
    const unsigned short* __restrict__ qb, const unsigned short* __restrict__ kvb,
    const unsigned short* __restrict__ kpe, unsigned short* __restrict__ o)
{
  __shared__ unsigned short Ks[64 * 200];      // [k][d 0..191], stride 200
  __shared__ unsigned short Vt[128 * 72];      // [vd][k], stride 72
  __shared__ unsigned short Ps[4 * 16 * 72];   // per-wave [m][k], stride 72

  const int t = threadIdx.x;
  const int qt = (int)gridDim.x - 1 - (int)blockIdx.x;  // longest first
  const int h = blockIdx.y, b = blockIdx.z;
  const int w = t >> 6, lane = t & 63;
  const int lm = lane & 15, lq = lane >> 4;
  const float SCALE = 0.07216878364870322f;  // 192^-0.5

  const unsigned short* qp = qb + (((size_t)b * S_ + (qt << 6) + (w << 4) + lm) * NH_ + h) * QHD_;
  bf16x8 qf[6];
#pragma unroll
  for (int s = 0; s < 6; ++s) qf[s] = *(const bf16x8*)(qp + s * 32 + (lq << 3));

  const floatx4 vzero = {0.f, 0.f, 0.f, 0.f};
  floatx4 of[8];
#pragma unroll
  for (int i = 0; i < 8; ++i) of[i] = vzero;
  float mrow[4] = {-1e30f, -1e30f, -1e30f, -1e30f};
  float lrow[4] = {0.f, 0.f, 0.f, 0.f};

  const unsigned short* kvbase = kvb + (size_t)(b * NH_ + h) * S_ * 256;
  const unsigned short* kpbase = kpe + (size_t)b * S_ * 64;

  for (int kt = 0; kt <= qt; ++kt) {
    const unsigned short* kvt = kvbase + (size_t)(kt << 6) * 256;
    const unsigned short* kpt = kpbase + (size_t)(kt << 6) * 64;
    __syncthreads();
#pragma unroll
    for (int it = 0; it < 4; ++it) {
      const int c = it * 256 + t;
      const int r = c >> 4, cc = (c & 15) << 3;
      *(uint4*)&Ks[r * 200 + cc] = *(const uint4*)(kvt + r * 256 + cc);
    }
#pragma unroll
    for (int it = 0; it < 2; ++it) {
      const int c = it * 256 + t;
      const int r = c >> 3, cc = (c & 7) << 3;
      *(uint4*)&Ks[r * 200 + 128 + cc] = *(const uint4*)(kpt + r * 64 + cc);
    }
#pragma unroll
    for (int it = 0; it < 2; ++it) {
      const int idx = it * 256 + t;
      const int cg = idx & 15, kp = idx >> 4;
      const unsigned short* p0 = kvt + (kp << 1) * 256 + 128 + (cg << 3);
      const uint4 va = *(const uint4*)p0;
      const uint4 vb = *(const uint4*)(p0 + 256);
      const unsigned short* ap = (const unsigned short*)&va;
      const unsigned short* bp = (const unsigned short*)&vb;
#pragma unroll
      for (int i = 0; i < 8; ++i)
        *(unsigned int*)&Vt[((cg << 3) + i) * 72 + (kp << 1)] =
            (unsigned int)ap[i] | ((unsigned int)bp[i] << 16);
    }
    __syncthreads();

    const bool diag = (kt == qt);
    const int nimax = diag ? w : 3;

    floatx4 sacc[4];
#pragma unroll
    for (int ni = 0; ni < 4; ++ni) sacc[ni] = vzero;
    for (int ni = 0; ni <= nimax; ++ni) {
#pragma unroll
      for (int s = 0; s < 6; ++s) {
        const bf16x8 kf = *(const bf16x8*)&Ks[(ni * 16 + lm) * 200 + s * 32 + (lq << 3)];
        sacc[ni] = __builtin_amdgcn_mfma_f32_16x16x32_bf16(qf[s], kf, sacc[ni], 0, 0, 0);
      }
    }

#pragma unroll
    for (int r = 0; r < 4; ++r) {
      const int rq = (lq << 2) + r;
      float sc[4], mx = -1e30f;
#pragma unroll
      for (int ni = 0; ni < 4; ++ni) {
        float v = sacc[ni][r] * SCALE;
        if (ni > nimax) v = -1e30f;
        if (diag && ni == w && lm > rq) v = -1e30f;
        sc[ni] = v;
        mx = fmaxf(mx, v);
      }
#pragma unroll
      for (int off = 8; off; off >>= 1) mx = fmaxf(mx, __shfl_xor(mx, off));
      const float mnew = fmaxf(mrow[r], mx);
      const float al = __expf(mrow[r] - mnew);
      mrow[r] = mnew;
      float ps = 0.f;
#pragma unroll
      for (int ni = 0; ni < 4; ++ni) {
        const float p = __expf(sc[ni] - mnew);
        ps += p;
        Ps[(w * 16 + rq) * 72 + ni * 16 + lm] = f2bf(p);
      }
#pragma unroll
      for (int off = 8; off; off >>= 1) ps += __shfl_xor(ps, off);
      lrow[r] = lrow[r] * al + ps;
#pragma unroll
      for (int vt = 0; vt < 8; ++vt) of[vt][r] *= al;
    }

    const int ksmax = diag ? ((w >= 2) ? 1 : 0) : 1;
    for (int ks2 = 0; ks2 <= ksmax; ++ks2) {
      const bf16x8 pf = *(const bf16x8*)&Ps[(w * 16 + lm) * 72 + ks2 * 32 + (lq << 3)];
#pragma unroll
      for (int vt = 0; vt < 8; ++vt) {
        const bf16x8 vf = *(const bf16x8*)&Vt[(vt * 16 + lm) * 72 + ks2 * 32 + (lq << 3)];
        of[vt] = __builtin_amdgcn_mfma_f32_16x16x32_bf16(pf, vf, of[vt], 0, 0, 0);
      }
    }
  }

#pragma unroll
  for (int r = 0; r < 4; ++r) {
    const int qrow = (qt << 6) + (w << 4) + (lq << 2) + r;
    const float inv = 1.f / lrow[r];
    unsigned short* orow = o + ((size_t)b * S_ + qrow) * 4096 + h * 128;
#pragma unroll
    for (int vt = 0; vt < 8; ++vt)
      orow[vt * 16 + lm] = f2bf(of[vt][r] * inv);
  }
}

// ---------------------------------------------------------------------------
extern "C" void kernel_launch(void* const* d_in, const int* in_sizes, int n_in,
                              void* d_out, int out_size, void* d_ws, size_t ws_size,
                              hipStream_t stream) {
  (void)in_sizes; (void)n_in; (void)out_size; (void)ws_size;
  const float* hs   = (const float*)d_in[0];
  const float* cosp = (const float*)d_in[1];
  const float* sinp = (const float*)d_in[2];
  const int*   pos  = (const int*)d_in[3];
  const float* Wqa  = (const float*)d_in[4];
  const float* gqa  = (const float*)d_in[5];
  const float* bqa  = (const float*)d_in[6];
  const float* Wqb  = (const float*)d_in[7];
  const float* Wkva = (const float*)d_in[8];
  const float* gkva = (const float*)d_in[9];
  const float* bkva = (const float*)d_in[10];
  const float* Wkvb = (const float*)d_in[11];
  const float* Wo   = (const float*)d_in[12];
  float* out = (float*)d_out;

  char* ws = (char*)d_ws;
  // lifetime-aliased workspace (~204.5 MiB total)
  unsigned short* hsb   = (unsigned short*)(ws);               // 33,554,432
  float*          q_a   = (float*)(ws + 33554432);             // 25,165,824
  unsigned short* qb    = (unsigned short*)(ws);               // alias over hsb+q_a (50,331,648 <= 58,720,256)
  unsigned short* WqaT  = (unsigned short*)(ws + 58720256);    // 12,582,912 (1536x4096)
  unsigned short* WkvaT = (unsigned short*)(ws + 71303168);    //  5,242,880 (640x4096, rows 576+ poison)
  unsigned short* qln   = (unsigned short*)(ws + 58720256);    // alias over WqaT (12,582,912)
  unsigned short* kvln  = (unsigned short*)(ws + 71303168);    // alias over WkvaT (4,194,304)
  unsigned short* WqbT  = (unsigned short*)(ws + 76546048);    // 18,874,368 (6144x1536)
  float*          ckv   = (float*)(ws + 95420416);             //  9,437,184
  unsigned short* WkvbT = (unsigned short*)(ws + 104857600);   //  8,388,608 (8192x512)
  unsigned short* ob    = (unsigned short*)(ws + 76546048);    // alias over WqbT+ckv+WkvbT (33,554,432 <= 36,700,160)
  unsigned short* WoT   = (unsigned short*)(ws + 113246208);   // 33,554,432 (4096x4096)
  unsigned short* kvb   = (unsigned short*)(ws + 146800640);   // 67,108,864 (B,NH,S,256)
  unsigned short* kpe   = (unsigned short*)(ws + 213909504);   //    524,288

  const dim3 blk(256);
  // prepass: bf16 convert + weight transposes
  convert_kernel<<<dim3(8192), blk, 0, stream>>>(hs, hsb);
  transpose_kernel<<<dim3(48, 128), blk, 0, stream>>>(Wqa, WqaT, 4096, 1536);
  transpose_kernel<<<dim3(18, 128), blk, 0, stream>>>(Wkva, WkvaT, 4096, 576);
  transpose_kernel<<<dim3(192, 48), blk, 0, stream>>>(Wqb, WqbT, 1536, 6144);
  transpose_kernel<<<dim3(256, 16), blk, 0, stream>>>(Wkvb, WkvbT, 512, 8192);
  transpose_kernel<<<dim3(128, 128), blk, 0, stream>>>(Wo, WoT, 4096, 4096);

  // q_a = hs @ Wqa ; ckv = hs @ Wkva
  gemm_bt<0><<<dim3(32, 12), blk, 0, stream>>>(hsb, WqaT, q_a, 1536, 4096, 4096, 4096, 1536);
  gemm_bt<0><<<dim3(32, 5), blk, 0, stream>>>(hsb, WkvaT, ckv, 576, 4096, 4096, 4096, 576);
  // LN -> bf16 (qln over WqaT, kvln over WkvaT — both weights dead now)
  ln_kernel<<<dim3(4096), blk, 0, stream>>>(q_a, gqa, bqa, qln, 1536, 1536, 1536);
  ln_kernel<<<dim3(4096), blk, 0, stream>>>(ckv, gkva, bkva, kvln, 512, 576, 512);
  rope_k_kernel<<<dim3(512), blk, 0, stream>>>(ckv, cosp, sinp, pos, kpe);
  // qb = qln @ Wqb (qb over hsb+q_a — both dead now)
  gemm_bt<1><<<dim3(32, 48), blk, 0, stream>>>(qln, WqbT, qb, 6144, 1536, 1536, 1536, 6144);
  rope_q_kernel<<<dim3(16384), blk, 0, stream>>>(qb, cosp, sinp, pos);
  // kvb = kvln @ Wkvb, scattered to (B,NH,S,256)
  gemm_bt<2><<<dim3(32, 64), blk, 0, stream>>>(kvln, WkvbT, kvb, 8192, 512, 512, 512, 8192);
  // attention (ob over WqbT+ckv+WkvbT — all dead now)
  attn_kernel<<<dim3(16, 32, 4), blk, 0, stream>>>(qb, kvb, kpe, ob);
  // out = ob @ Wo
  gemm_bt<0><<<dim3(32, 32), blk, 0, stream>>>(ob, WoT, out, 4096, 4096, 4096, 4096, 4096);
}